// Round 9
// baseline (179.889 us; speedup 1.0000x reference)
//
#include <hip/hip_runtime.h>
#include <stdint.h>

// S=4096, D=64.  out = (t * floor(t*rr)/R) @ V,  t = (QK^T*8) * dropout_keep/0.9
// R9: SPLIT the fused kernel. R5-R8 proved the fused structure's serial
// per-tile chain (u -> QK -> epilogue -> relayout -> PV) is the binder
// (40-56us across 3 different latency-hiding schemes). Now:
//   score_kernel: 4096 tiny blocks, one 64x64 tile each -> P (bf16, 32MB ws)
//                 + sum(r). HBM-bound stream, TLP-hidden, no serial chain.
//   pv_kernel:    out = P @ V, clean GEMM on cache-resident P, reg-pipelined.
// Extra 64MB traffic (~10us) buys removal of the ~30us serial-chain tax.

#define S 4096
#define D 64
#define NCHUNK 16             // k-chunks in pv_kernel (grid 64*16 = 1024)
#define KCHUNK (S / NCHUNK)   // 256
#define KSTEPS (KCHUNK / 32)  // 8
#define KSCALE (8.0f / 0.9f)

typedef float f32x4 __attribute__((ext_vector_type(4)));
typedef short s16x8 __attribute__((ext_vector_type(8)));
typedef unsigned short u16x4 __attribute__((ext_vector_type(4)));

__device__ inline unsigned short f2bf(float f) {
    union { float f; unsigned u; } v; v.f = f;
    unsigned r = v.u + 0x7fffu + ((v.u >> 16) & 1u);
    return (unsigned short)(r >> 16);
}

// ---- prep: Q->bf16, K->bf16*KSCALE (blocks 0..511), V->V^T (512..575) ----
__global__ void prep_all(const float* __restrict__ Q,
                         const float* __restrict__ Kf,
                         const float* __restrict__ V,
                         short* __restrict__ Qbf, short* __restrict__ Kbf,
                         short* __restrict__ VTbf, int* __restrict__ sumr) {
    __shared__ short tile[64 * 68];
    const int b   = blockIdx.x;
    const int tid = threadIdx.x;
    if (b == 0 && tid == 0) *sumr = 0;

    if (b < 512) {
        const int idx = b * 256 + tid;               // 131072 float4 slots
        if (idx < 65536) {
            float4 v = ((const float4*)Q)[idx];
            u16x4 o; o[0] = f2bf(v.x); o[1] = f2bf(v.y); o[2] = f2bf(v.z); o[3] = f2bf(v.w);
            ((u16x4*)Qbf)[idx] = o;
        } else {
            const int k = idx - 65536;
            float4 v = ((const float4*)Kf)[k];
            u16x4 o; o[0] = f2bf(v.x * KSCALE); o[1] = f2bf(v.y * KSCALE);
                     o[2] = f2bf(v.z * KSCALE); o[3] = f2bf(v.w * KSCALE);
            ((u16x4*)Kbf)[k] = o;
        }
    } else {
        const int j0 = (b - 512) * 64;
#pragma unroll
        for (int it = 0; it < 4; ++it) {
            const int f4 = tid + it * 256;
            const int row = f4 >> 4, c4 = (f4 & 15) * 4;
            float4 v = *(const float4*)&V[(size_t)(j0 + row) * D + c4];
            tile[(c4 + 0) * 68 + row] = (short)f2bf(v.x);
            tile[(c4 + 1) * 68 + row] = (short)f2bf(v.y);
            tile[(c4 + 2) * 68 + row] = (short)f2bf(v.z);
            tile[(c4 + 3) * 68 + row] = (short)f2bf(v.w);
        }
        __syncthreads();
#pragma unroll
        for (int it = 0; it < 4; ++it) {
            const int f4 = tid + it * 256;
            const int d = f4 >> 4, o4 = (f4 & 15) * 4;
            u16x4 w = *(const u16x4*)&tile[d * 68 + o4];
            *(u16x4*)&VTbf[(size_t)d * S + j0 + o4] = w;
        }
    }
}

// ---- score: one 64x64 tile per block. QK^T -> mask/floor -> P (bf16) + sum(r) ----
__launch_bounds__(256, 4)
__global__ void score_kernel(const short* __restrict__ Qbf,
                             const short* __restrict__ Kbf,
                             const float* __restrict__ Ud,
                             const float* __restrict__ RR,
                             short* __restrict__ Pbuf,     // [S][S] bf16
                             int* __restrict__ sumr)
{
    __shared__ int red[4];
    const int tid  = threadIdx.x;
    const int w    = tid >> 6;
    const int lane = tid & 63;
    const int quad = lane >> 4;
    const int n16  = lane & 15;

    const int ib  = blockIdx.x & 63;          // i-tile
    const int jb  = blockIdx.x >> 6;          // j-tile
    const int i0w = ib * 64 + w * 16;
    const int j0  = jb * 64;

    // u for this lane's 16 C-layout positions — issue FIRST (longest latency)
    float uv[16];
#pragma unroll
    for (int e = 0; e < 16; ++e) {
        const int cs = e >> 2, rg = e & 3;
        uv[e] = __builtin_nontemporal_load(
            &Ud[(size_t)(i0w + quad * 4 + rg) * S + j0 + cs * 16 + n16]);
    }

    s16x8 aQ[2];
#pragma unroll
    for (int ks = 0; ks < 2; ++ks)
        aQ[ks] = *(const s16x8*)&Qbf[(size_t)(i0w + n16) * D + ks * 32 + quad * 8];

    s16x8 kf[8];
#pragma unroll
    for (int e = 0; e < 8; ++e) {
        const int cs = e >> 1, ks = e & 1;
        kf[e] = *(const s16x8*)&Kbf[(size_t)(j0 + cs * 16 + n16) * D + ks * 32 + quad * 8];
    }

    float rr[4];
#pragma unroll
    for (int rg = 0; rg < 4; ++rg) rr[rg] = RR[i0w + quad * 4 + rg];

    f32x4 accqk[4];
#pragma unroll
    for (int cs = 0; cs < 4; ++cs) {
        f32x4 acc = (f32x4){0.f, 0.f, 0.f, 0.f};
#pragma unroll
        for (int ks = 0; ks < 2; ++ks)
            acc = __builtin_amdgcn_mfma_f32_16x16x32_bf16(aQ[ks], kf[cs * 2 + ks], acc, 0, 0, 0);
        accqk[cs] = acc;
    }

    // epilogue: dropout + floor; write P in C-native positions (bf16 scalar)
    float lsum = 0.f;
#pragma unroll
    for (int cs = 0; cs < 4; ++cs) {
#pragma unroll
        for (int rg = 0; rg < 4; ++rg) {
            const float t = (uv[cs * 4 + rg] >= 0.1f) ? accqk[cs][rg] : 0.0f;  // KSCALE folded in Kbf
            const float r = floorf(t * rr[rg]);
            lsum += r;                        // r are small integers; fp32 exact
            ((unsigned short*)Pbuf)[(size_t)(i0w + quad * 4 + rg) * S + j0 + cs * 16 + n16]
                = f2bf(t * r);
        }
    }

    // sum(r): wave shuffle -> LDS -> one atomic per block
    for (int off = 32; off; off >>= 1) lsum += __shfl_down(lsum, off);
    if (lane == 0) red[w] = (int)lsum;
    __syncthreads();
    if (tid == 0) atomicAdd(sumr, red[0] + red[1] + red[2] + red[3]);
}

// ---- pv: out_partial = P @ V over one k-chunk (reg-double-buffered GEMM) ----
__launch_bounds__(256, 4)
__global__ void pv_kernel(const short* __restrict__ Pbuf,
                          const short* __restrict__ VTbf,
                          float* __restrict__ Opart)       // [NCHUNK][S][D]
{
    const int tid  = threadIdx.x;
    const int w    = tid >> 6;
    const int lane = tid & 63;
    const int quad = lane >> 4;
    const int n16  = lane & 15;

    const int ib    = blockIdx.x & 63;
    const int ic    = blockIdx.x >> 6;        // k-chunk 0..15
    const int i0w   = ib * 64 + w * 16;
    const int kbase = ic * KCHUNK;

    f32x4 accO[4];
#pragma unroll
    for (int ds = 0; ds < 4; ++ds) accO[ds] = (f32x4){0.f, 0.f, 0.f, 0.f};

    s16x8 aP[2];
    s16x8 vf[2][4];

    // prefetch kstep 0
    aP[0] = *(const s16x8*)&Pbuf[(size_t)(i0w + n16) * S + kbase + quad * 8];
#pragma unroll
    for (int ds = 0; ds < 4; ++ds)
        vf[0][ds] = *(const s16x8*)&VTbf[(size_t)(ds * 16 + n16) * S + kbase + quad * 8];

#pragma unroll
    for (int kk = 0; kk < KSTEPS; ++kk) {
        const int bu = kk & 1;
        if (kk + 1 < KSTEPS) {
            const int nb = bu ^ 1;
            const int k1 = kbase + (kk + 1) * 32 + quad * 8;
            aP[nb] = *(const s16x8*)&Pbuf[(size_t)(i0w + n16) * S + k1];
#pragma unroll
            for (int ds = 0; ds < 4; ++ds)
                vf[nb][ds] = *(const s16x8*)&VTbf[(size_t)(ds * 16 + n16) * S + k1];
        }
#pragma unroll
        for (int ds = 0; ds < 4; ++ds)
            accO[ds] = __builtin_amdgcn_mfma_f32_16x16x32_bf16(aP[bu], vf[bu][ds], accO[ds], 0, 0, 0);
    }

    float* op = Opart + (size_t)ic * S * D;
#pragma unroll
    for (int ds = 0; ds < 4; ++ds) {
        const int d = ds * 16 + n16;
#pragma unroll
        for (int rg = 0; rg < 4; ++rg)
            op[(size_t)(i0w + quad * 4 + rg) * D + d] = accO[ds][rg];
    }
}

// ---- reduce partials over NCHUNK + apply 1/R ----
__global__ void reduce_out(const float* __restrict__ Opart,
                           const int* __restrict__ sumr,
                           float* __restrict__ out) {
    const int idx = blockIdx.x * 256 + threadIdx.x;   // 65536 float4 groups
    const float invR = 1.0f / (float)(*sumr);         // |R| < 2^24: exact
    float sx = 0.f, sy = 0.f, sz = 0.f, sw = 0.f;
#pragma unroll
    for (int c = 0; c < NCHUNK; ++c) {
        const float4 v = ((const float4*)(Opart + (size_t)c * S * D))[idx];
        sx += v.x; sy += v.y; sz += v.z; sw += v.w;
    }
    float4 o; o.x = sx * invR; o.y = sy * invR; o.z = sz * invR; o.w = sw * invR;
    ((float4*)out)[idx] = o;
}

extern "C" void kernel_launch(void* const* d_in, const int* in_sizes, int n_in,
                              void* d_out, int out_size, void* d_ws, size_t ws_size,
                              hipStream_t stream) {
    (void)in_sizes; (void)n_in; (void)out_size; (void)ws_size;
    const float* Q  = (const float*)d_in[0];
    const float* Kf = (const float*)d_in[1];
    const float* V  = (const float*)d_in[2];
    const float* Ud = (const float*)d_in[3];
    const float* RR = (const float*)d_in[4];
    float* out = (float*)d_out;

    // ws layout: Pbuf 32MB | Opart 16MB | Qbf 512KB | Kbf 512KB | VTbf 512KB | sumr
    char* ws = (char*)d_ws;
    short* Pbuf  = (short*)ws;                                  // 32 MB
    float* Opart = (float*)(ws + (32u << 20));                  // 16 MB
    short* Qbf  = (short*)(ws + (48u << 20));
    short* Kbf  = (short*)(ws + (48u << 20) + (512u << 10));
    short* VTbf = (short*)(ws + (48u << 20) + (1024u << 10));
    int*   sumr = (int*)  (ws + (48u << 20) + (1536u << 10));

    prep_all<<<dim3(576), dim3(256), 0, stream>>>(Q, Kf, V, Qbf, Kbf, VTbf, sumr);
    score_kernel<<<dim3(64 * 64), dim3(256), 0, stream>>>(Qbf, Kbf, Ud, RR, Pbuf, sumr);
    pv_kernel<<<dim3(64 * NCHUNK), dim3(256), 0, stream>>>(Pbuf, VTbf, Opart);
    reduce_out<<<dim3(256), dim3(256), 0, stream>>>(Opart, sumr, out);
}

// Round 10
// 138.355 us; speedup vs baseline: 1.3002x; 1.3002x over previous
//
#include <hip/hip_runtime.h>
#include <stdint.h>

// S=4096, D=64.  out = (t * floor(t*rr)/R) @ V,  t = (QK^T*8) * dropout_keep/0.9
// R10: R5's fused skeleton (4 tiles/block, reg-dbuf kf, wave-private pb,
// no block barriers) + u streamed IN-LOOP as 4 coalesced b128 loads/tile
// (pack_mask's 5TB/s shape), packed to a 16-bit lane mask at tile END
// (off critical path), delivered to C-layout via 16 ds_bpermute (in-wave).
// Removes both the 11us serial pack prefix (R5) and scalar-u latency (R6).

#define S 4096
#define D 64
#define NCHUNK 16             // grid = 64 i-blocks * 16 chunks = 1024 blocks
#define JCHUNK (S / NCHUNK)   // 256
#define NTILES (JCHUNK / 64)  // 4
#define LDP 72                // pb row pitch in shorts
#define KSCALE (8.0f / 0.9f)

typedef float f32x4 __attribute__((ext_vector_type(4)));
typedef short s16x8 __attribute__((ext_vector_type(8)));
typedef unsigned short u16x4 __attribute__((ext_vector_type(4)));

__device__ inline unsigned short f2bf(float f) {
    union { float f; unsigned u; } v; v.f = f;
    unsigned r = v.u + 0x7fffu + ((v.u >> 16) & 1u);
    return (unsigned short)(r >> 16);
}

// ---- prep: Q->bf16, K->bf16*KSCALE (blocks 0..511), V->V^T (512..575) ----
__global__ void prep_all(const float* __restrict__ Q,
                         const float* __restrict__ Kf,
                         const float* __restrict__ V,
                         short* __restrict__ Qbf, short* __restrict__ Kbf,
                         short* __restrict__ VTbf, int* __restrict__ sumr) {
    __shared__ short tile[64 * 68];
    const int b   = blockIdx.x;
    const int tid = threadIdx.x;
    if (b == 0 && tid == 0) *sumr = 0;

    if (b < 512) {
        const int idx = b * 256 + tid;               // 131072 float4 slots
        if (idx < 65536) {
            float4 v = ((const float4*)Q)[idx];
            u16x4 o; o[0] = f2bf(v.x); o[1] = f2bf(v.y); o[2] = f2bf(v.z); o[3] = f2bf(v.w);
            ((u16x4*)Qbf)[idx] = o;
        } else {
            const int k = idx - 65536;
            float4 v = ((const float4*)Kf)[k];
            u16x4 o; o[0] = f2bf(v.x * KSCALE); o[1] = f2bf(v.y * KSCALE);
                     o[2] = f2bf(v.z * KSCALE); o[3] = f2bf(v.w * KSCALE);
            ((u16x4*)Kbf)[k] = o;
        }
    } else {
        const int j0 = (b - 512) * 64;
#pragma unroll
        for (int it = 0; it < 4; ++it) {
            const int f4 = tid + it * 256;
            const int row = f4 >> 4, c4 = (f4 & 15) * 4;
            float4 v = *(const float4*)&V[(size_t)(j0 + row) * D + c4];
            tile[(c4 + 0) * 68 + row] = (short)f2bf(v.x);
            tile[(c4 + 1) * 68 + row] = (short)f2bf(v.y);
            tile[(c4 + 2) * 68 + row] = (short)f2bf(v.z);
            tile[(c4 + 3) * 68 + row] = (short)f2bf(v.w);
        }
        __syncthreads();
#pragma unroll
        for (int it = 0; it < 4; ++it) {
            const int f4 = tid + it * 256;
            const int d = f4 >> 4, o4 = (f4 & 15) * 4;
            u16x4 w = *(const u16x4*)&tile[d * 68 + o4];
            *(u16x4*)&VTbf[(size_t)d * S + j0 + o4] = w;
        }
    }
}

// load one wave's 16x64 u-tile in streaming shape and pack to a 16-bit lane
// mask: lane l holds bits for rows {q*4 + l>>4} x cols {(l&15)*4 + c},
// bit index q*4+c.  (4 x b128 loads, 256B contiguous per 16-lane segment)
__device__ __forceinline__ unsigned load_pack_u(const float* __restrict__ ub,
                                                int lane) {
    unsigned m = 0;
#pragma unroll
    for (int q = 0; q < 4; ++q) {
        const float4 uq = *(const float4*)&ub[(size_t)(q * 4 + (lane >> 4)) * S + (lane & 15) * 4];
        m |= (uq.x >= 0.1f ? 1u : 0u) << (q * 4 + 0);
        m |= (uq.y >= 0.1f ? 1u : 0u) << (q * 4 + 1);
        m |= (uq.z >= 0.1f ? 1u : 0u) << (q * 4 + 2);
        m |= (uq.w >= 0.1f ? 1u : 0u) << (q * 4 + 3);
    }
    return m;
}

// ---- main: barrier-free, reg-pipelined, in-loop streamed u ----
__launch_bounds__(256, 3)
__global__ void fused_main(const short* __restrict__ Qbf,
                           const short* __restrict__ Kbf,
                           const short* __restrict__ VTbf,
                           const float* __restrict__ Ud,
                           const float* __restrict__ RR,
                           float* __restrict__ Opart,            // [NCHUNK][S][D]
                           int* __restrict__ sumr)
{
    __shared__ short pb[4 * 16 * LDP];
    __shared__ int red[4];

    const int tid  = threadIdx.x;
    const int w    = tid >> 6;
    const int lane = tid & 63;
    const int quad = lane >> 4;
    const int n16  = lane & 15;

    const int ib  = blockIdx.x & 63;
    const int ic  = blockIdx.x >> 6;
    const int i0w = ib * 64 + w * 16;
    const int jbase = ic * JCHUNK;

    const float* uwb = Ud + (size_t)i0w * S;   // this wave's 16 u rows

    s16x8 aQ[2];
#pragma unroll
    for (int ks = 0; ks < 2; ++ks)
        aQ[ks] = *(const s16x8*)&Qbf[(size_t)(i0w + n16) * D + ks * 32 + quad * 8];

    float rr[4];
#pragma unroll
    for (int rg = 0; rg < 4; ++rg) rr[rg] = RR[i0w + quad * 4 + rg];

    f32x4 accO[4];
#pragma unroll
    for (int ds = 0; ds < 4; ++ds) accO[ds] = (f32x4){0.f, 0.f, 0.f, 0.f};

    float lsum = 0.f;                 // r are small integers; fp32 sum exact
    short* pw = pb + w * 16 * LDP;

    s16x8 kf[2][8];      // K-frags, register double-buffered
    unsigned um[2];      // packed u masks, double-buffered (1 VGPR each)

    // bpermute byte-index per (cs,rg): src lane = rg*16 + cs*4 + (n16>>2)
    const int bsel = quad * 4 + (n16 & 3);     // bit within fetched mask
    const int bidx0 = (n16 >> 2) * 4;          // byte index base

    // prologue: u(t0) pack + K-frags(t0)
    um[0] = load_pack_u(uwb + jbase, lane);
#pragma unroll
    for (int e = 0; e < 8; ++e) {
        const int cs = e >> 1, ks = e & 1;
        kf[0][e] = *(const s16x8*)&Kbf[(size_t)(jbase + cs * 16 + n16) * D + ks * 32 + quad * 8];
    }

#pragma unroll
    for (int jt = 0; jt < NTILES; ++jt) {
        const int bu = jt & 1;
        const int nb = bu ^ 1;
        const int j0 = jbase + jt * 64;
        const int last = (jt + 1 == NTILES);

        // (a) issue NEXT tile's u stream (raw float4s; packed at tile end)
        float4 un[4];
        if (!last) {
            const float* ub = uwb + j0 + 64;
#pragma unroll
            for (int q = 0; q < 4; ++q)
                un[q] = *(const float4*)&ub[(size_t)(q * 4 + (lane >> 4)) * S + (lane & 15) * 4];
        }

        // (b) V-frags for THIS tile (consumed at tile end)
        s16x8 vf[8];
#pragma unroll
        for (int e = 0; e < 8; ++e) {
            const int ksj = e >> 2, ds = e & 3;
            vf[e] = *(const s16x8*)&VTbf[(size_t)(ds * 16 + n16) * S + j0 + ksj * 32 + quad * 8];
        }

        // (c) K-frags for NEXT tile
        if (!last) {
#pragma unroll
            for (int e = 0; e < 8; ++e) {
                const int cs = e >> 1, ks = e & 1;
                kf[nb][e] = *(const s16x8*)&Kbf[(size_t)(j0 + 64 + cs * 16 + n16) * D + ks * 32 + quad * 8];
            }
        }

        // (d) QK^T on current K buffer
        f32x4 accqk[4];
#pragma unroll
        for (int cs = 0; cs < 4; ++cs) {
            f32x4 acc = (f32x4){0.f, 0.f, 0.f, 0.f};
#pragma unroll
            for (int ks = 0; ks < 2; ++ks)
                acc = __builtin_amdgcn_mfma_f32_16x16x32_bf16(aQ[ks], kf[bu][cs * 2 + ks], acc, 0, 0, 0);
            accqk[cs] = acc;
        }

        // (e) epilogue: fetch keep-bit via in-wave bpermute; floor mask; -> pb
#pragma unroll
        for (int cs = 0; cs < 4; ++cs) {
#pragma unroll
            for (int rg = 0; rg < 4; ++rg) {
                const int mv = __builtin_amdgcn_ds_bpermute(
                    (rg * 16 + cs * 4) * 4 + bidx0, (int)um[bu]);
                const float t = ((((unsigned)mv) >> bsel) & 1u) ? accqk[cs][rg] : 0.0f;
                const float r = floorf(t * rr[rg]);
                lsum += r;
                pw[(quad * 4 + rg) * LDP + cs * 16 + n16] = (short)f2bf(t * r);
            }
        }

        // (f) within-wave LDS drain for pb (bpermute is lgkm too — ok)
        __builtin_amdgcn_wave_barrier();
        __asm__ volatile("s_waitcnt lgkmcnt(0)" ::: "memory");
        __builtin_amdgcn_wave_barrier();

        // (g) PV
#pragma unroll
        for (int ksj = 0; ksj < 2; ++ksj) {
            s16x8 aP = *(const s16x8*)&pw[n16 * LDP + ksj * 32 + quad * 8];
#pragma unroll
            for (int ds = 0; ds < 4; ++ds)
                accO[ds] = __builtin_amdgcn_mfma_f32_16x16x32_bf16(aP, vf[ksj * 4 + ds], accO[ds], 0, 0, 0);
        }
        __builtin_amdgcn_wave_barrier();   // pb reuse fence

        // (h) pack next tile's u mask (loads had the whole tile to land;
        //     accqk/vf dead here -> low register peak)
        if (!last) {
            unsigned m = 0;
#pragma unroll
            for (int q = 0; q < 4; ++q) {
                m |= (un[q].x >= 0.1f ? 1u : 0u) << (q * 4 + 0);
                m |= (un[q].y >= 0.1f ? 1u : 0u) << (q * 4 + 1);
                m |= (un[q].z >= 0.1f ? 1u : 0u) << (q * 4 + 2);
                m |= (un[q].w >= 0.1f ? 1u : 0u) << (q * 4 + 3);
            }
            um[nb] = m;
        }
    }

    // deterministic partial stores (full 64B segments)
    float* op = Opart + (size_t)ic * S * D;
#pragma unroll
    for (int ds = 0; ds < 4; ++ds) {
        const int d = ds * 16 + n16;
#pragma unroll
        for (int rg = 0; rg < 4; ++rg) {
            const int i = i0w + quad * 4 + rg;
            op[(size_t)i * D + d] = accO[ds][rg];
        }
    }

    // sum(r): wave shuffle -> LDS -> one int atomic per block
    for (int off = 32; off; off >>= 1) lsum += __shfl_down(lsum, off);
    if (lane == 0) red[w] = (int)lsum;
    __syncthreads();
    if (tid == 0) atomicAdd(sumr, red[0] + red[1] + red[2] + red[3]);
}

// ---- reduce partials over NCHUNK + apply 1/R ----
__global__ void reduce_out(const float* __restrict__ Opart,
                           const int* __restrict__ sumr,
                           float* __restrict__ out) {
    const int idx = blockIdx.x * 256 + threadIdx.x;   // 65536 float4 groups
    const float invR = 1.0f / (float)(*sumr);         // |R| < 2^24: exact
    float sx = 0.f, sy = 0.f, sz = 0.f, sw = 0.f;
#pragma unroll
    for (int c = 0; c < NCHUNK; ++c) {
        const float4 v = ((const float4*)(Opart + (size_t)c * S * D))[idx];
        sx += v.x; sy += v.y; sz += v.z; sw += v.w;
    }
    float4 o; o.x = sx * invR; o.y = sy * invR; o.z = sz * invR; o.w = sw * invR;
    ((float4*)out)[idx] = o;
}

extern "C" void kernel_launch(void* const* d_in, const int* in_sizes, int n_in,
                              void* d_out, int out_size, void* d_ws, size_t ws_size,
                              hipStream_t stream) {
    (void)in_sizes; (void)n_in; (void)out_size; (void)ws_size;
    const float* Q  = (const float*)d_in[0];
    const float* Kf = (const float*)d_in[1];
    const float* V  = (const float*)d_in[2];
    const float* Ud = (const float*)d_in[3];
    const float* RR = (const float*)d_in[4];
    float* out = (float*)d_out;

    // ws layout: Opart 16MB | Qbf 512KB | Kbf 512KB | VTbf 512KB | sumr
    char* ws = (char*)d_ws;
    float* Opart = (float*)ws;                                  // 16 MB
    short* Qbf  = (short*)(ws + (16u << 20));
    short* Kbf  = (short*)(ws + (16u << 20) + (512u << 10));
    short* VTbf = (short*)(ws + (16u << 20) + (1024u << 10));
    int*   sumr = (int*)  (ws + (16u << 20) + (1536u << 10));

    prep_all<<<dim3(576), dim3(256), 0, stream>>>(Q, Kf, V, Qbf, Kbf, VTbf, sumr);
    fused_main<<<dim3(64 * NCHUNK), dim3(256), 0, stream>>>(
        Qbf, Kbf, VTbf, Ud, RR, Opart, sumr);
    reduce_out<<<dim3(256), dim3(256), 0, stream>>>(Opart, sumr, out);
}

// Round 11
// 121.203 us; speedup vs baseline: 1.4842x; 1.1415x over previous
//
#include <hip/hip_runtime.h>
#include <stdint.h>

// S=4096, D=64.  out = (t * floor(t*rr)/R) @ V,  t = (QK^T*8) * dropout_keep/0.9
// R11: regalloc keeps sinking register prefetches (VGPR_Count 84-92 across
// R6/R10) -> move K/V staging to global_load_lds DMA (0 VGPRs, depth is
// structural). Fragment-major LDS layout (frag e at base+e*1024+lane*16 ==
// the DMA landing pattern; ds_read_b128 is a contiguous 1KB wave read).
// Tiles SHARED per block (not per wave): 2.5x less L2 traffic. Counted
// s_waitcnt vmcnt(8) + raw s_barrier (no __syncthreads full-drain).
// u keeps R10's direct-b128 + bitpack + bpermute epilogue.

#define S 4096
#define D 64
#define NCHUNK 8              // grid = 64 i-blocks * 8 chunks = 512 blocks
#define JCHUNK (S / NCHUNK)   // 512
#define NTILES (JCHUNK / 64)  // 8
#define LDP 72                // pb row pitch in shorts
#define KSCALE (8.0f / 0.9f)

typedef float f32x4 __attribute__((ext_vector_type(4)));
typedef short s16x8 __attribute__((ext_vector_type(8)));
typedef unsigned short u16x4 __attribute__((ext_vector_type(4)));
typedef const __attribute__((address_space(1))) unsigned g_u32;
typedef __attribute__((address_space(3))) unsigned lds_u32;

__device__ inline unsigned short f2bf(float f) {
    union { float f; unsigned u; } v; v.f = f;
    unsigned r = v.u + 0x7fffu + ((v.u >> 16) & 1u);
    return (unsigned short)(r >> 16);
}

// ---- prep: Q->bf16, K->bf16*KSCALE (blocks 0..511), V->V^T (512..575) ----
__global__ void prep_all(const float* __restrict__ Q,
                         const float* __restrict__ Kf,
                         const float* __restrict__ V,
                         short* __restrict__ Qbf, short* __restrict__ Kbf,
                         short* __restrict__ VTbf, int* __restrict__ sumr) {
    __shared__ short tile[64 * 68];
    const int b   = blockIdx.x;
    const int tid = threadIdx.x;
    if (b == 0 && tid == 0) *sumr = 0;

    if (b < 512) {
        const int idx = b * 256 + tid;               // 131072 float4 slots
        if (idx < 65536) {
            float4 v = ((const float4*)Q)[idx];
            u16x4 o; o[0] = f2bf(v.x); o[1] = f2bf(v.y); o[2] = f2bf(v.z); o[3] = f2bf(v.w);
            ((u16x4*)Qbf)[idx] = o;
        } else {
            const int k = idx - 65536;
            float4 v = ((const float4*)Kf)[k];
            u16x4 o; o[0] = f2bf(v.x * KSCALE); o[1] = f2bf(v.y * KSCALE);
                     o[2] = f2bf(v.z * KSCALE); o[3] = f2bf(v.w * KSCALE);
            ((u16x4*)Kbf)[k] = o;
        }
    } else {
        const int j0 = (b - 512) * 64;
#pragma unroll
        for (int it = 0; it < 4; ++it) {
            const int f4 = tid + it * 256;
            const int row = f4 >> 4, c4 = (f4 & 15) * 4;
            float4 v = *(const float4*)&V[(size_t)(j0 + row) * D + c4];
            tile[(c4 + 0) * 68 + row] = (short)f2bf(v.x);
            tile[(c4 + 1) * 68 + row] = (short)f2bf(v.y);
            tile[(c4 + 2) * 68 + row] = (short)f2bf(v.z);
            tile[(c4 + 3) * 68 + row] = (short)f2bf(v.w);
        }
        __syncthreads();
#pragma unroll
        for (int it = 0; it < 4; ++it) {
            const int f4 = tid + it * 256;
            const int d = f4 >> 4, o4 = (f4 & 15) * 4;
            u16x4 w = *(const u16x4*)&tile[d * 68 + o4];
            *(u16x4*)&VTbf[(size_t)d * S + j0 + o4] = w;
        }
    }
}

// ---- main ----
__launch_bounds__(256, 3)
__global__ void fused_main(const short* __restrict__ Qbf,
                           const short* __restrict__ Kbf,
                           const short* __restrict__ VTbf,
                           const float* __restrict__ Ud,
                           const float* __restrict__ RR,
                           float* __restrict__ Opart,            // [NCHUNK][S][D]
                           int* __restrict__ sumr)
{
    __shared__ short kb[2][4096];        // K tile, fragment-major: frag e = 1KB
    __shared__ short vb[2][4096];        // V^T tile, fragment-major
    __shared__ short pb[4 * 16 * LDP];   // per-wave P relayout
    __shared__ int red[4];

    const int tid  = threadIdx.x;
    const int w    = tid >> 6;
    const int lane = tid & 63;
    const int quad = lane >> 4;
    const int n16  = lane & 15;

    const int ib  = blockIdx.x & 63;
    const int ic  = blockIdx.x >> 6;     // 0..NCHUNK-1
    const int i0w = ib * 64 + w * 16;
    const int jbase = ic * JCHUNK;

    const float* uwb = Ud + (size_t)i0w * S;   // this wave's 16 u rows

    s16x8 aQ[2];
#pragma unroll
    for (int ks = 0; ks < 2; ++ks)
        aQ[ks] = *(const s16x8*)&Qbf[(size_t)(i0w + n16) * D + ks * 32 + quad * 8];

    float rr[4];
#pragma unroll
    for (int rg = 0; rg < 4; ++rg) rr[rg] = RR[i0w + quad * 4 + rg];

    f32x4 accO[4];
#pragma unroll
    for (int ds = 0; ds < 4; ++ds) accO[ds] = (f32x4){0.f, 0.f, 0.f, 0.f};

    float lsum = 0.f;
    short* pw = pb + w * 16 * LDP;

    unsigned um[2];            // packed u keep-bits (R10 scheme)
    const int bsel  = quad * 4 + (n16 & 3);
    const int bidx0 = (n16 >> 2) * 4;

    // per-wave DMA of 2 K-frags + 2 V-frags (block covers all 8 of each)
    const int e0 = w * 2, e1 = w * 2 + 1;

    // ---- prologue: tile 0 ----
    {
        const int j0 = jbase;
        // K frags e0,e1 -> kb[0]
        __builtin_amdgcn_global_load_lds(
            (g_u32*)&Kbf[(size_t)(j0 + (e0 >> 1) * 16 + n16) * D + (e0 & 1) * 32 + quad * 8],
            (lds_u32*)&kb[0][e0 * 512], 16, 0, 0);
        __builtin_amdgcn_global_load_lds(
            (g_u32*)&Kbf[(size_t)(j0 + (e1 >> 1) * 16 + n16) * D + (e1 & 1) * 32 + quad * 8],
            (lds_u32*)&kb[0][e1 * 512], 16, 0, 0);
        // V frags e0,e1 -> vb[0]   (e = ksj*4+ds)
        __builtin_amdgcn_global_load_lds(
            (g_u32*)&VTbf[(size_t)((e0 & 3) * 16 + n16) * S + j0 + (e0 >> 2) * 32 + quad * 8],
            (lds_u32*)&vb[0][e0 * 512], 16, 0, 0);
        __builtin_amdgcn_global_load_lds(
            (g_u32*)&VTbf[(size_t)((e1 & 3) * 16 + n16) * S + j0 + (e1 >> 2) * 32 + quad * 8],
            (lds_u32*)&vb[0][e1 * 512], 16, 0, 0);
        // u tile 0 (direct to regs, packed below)
        float4 u0[4];
#pragma unroll
        for (int q = 0; q < 4; ++q)
            u0[q] = *(const float4*)&uwb[(size_t)(q * 4 + quad) * S + j0 + n16 * 4];
        unsigned m = 0;
#pragma unroll
        for (int q = 0; q < 4; ++q) {
            m |= (u0[q].x >= 0.1f ? 1u : 0u) << (q * 4 + 0);
            m |= (u0[q].y >= 0.1f ? 1u : 0u) << (q * 4 + 1);
            m |= (u0[q].z >= 0.1f ? 1u : 0u) << (q * 4 + 2);
            m |= (u0[q].w >= 0.1f ? 1u : 0u) << (q * 4 + 3);
        }
        um[0] = m;
    }

#pragma unroll
    for (int jt = 0; jt < NTILES; ++jt) {
        const int bu = jt & 1;
        const int nb = bu ^ 1;
        const int j0 = jbase + jt * 64;
        const bool last = (jt + 1 == NTILES);

        // (a) issue NEXT tile's DMAs + u loads FIRST (4 DMA + 4 b128 = 8 vmem)
        float4 un[4];
        if (!last) {
            const int j1 = j0 + 64;
            __builtin_amdgcn_global_load_lds(
                (g_u32*)&Kbf[(size_t)(j1 + (e0 >> 1) * 16 + n16) * D + (e0 & 1) * 32 + quad * 8],
                (lds_u32*)&kb[nb][e0 * 512], 16, 0, 0);
            __builtin_amdgcn_global_load_lds(
                (g_u32*)&Kbf[(size_t)(j1 + (e1 >> 1) * 16 + n16) * D + (e1 & 1) * 32 + quad * 8],
                (lds_u32*)&kb[nb][e1 * 512], 16, 0, 0);
            __builtin_amdgcn_global_load_lds(
                (g_u32*)&VTbf[(size_t)((e0 & 3) * 16 + n16) * S + j1 + (e0 >> 2) * 32 + quad * 8],
                (lds_u32*)&vb[nb][e0 * 512], 16, 0, 0);
            __builtin_amdgcn_global_load_lds(
                (g_u32*)&VTbf[(size_t)((e1 & 3) * 16 + n16) * S + j1 + (e1 >> 2) * 32 + quad * 8],
                (lds_u32*)&vb[nb][e1 * 512], 16, 0, 0);
#pragma unroll
            for (int q = 0; q < 4; ++q)
                un[q] = *(const float4*)&uwb[(size_t)(q * 4 + quad) * S + j1 + n16 * 4];
        }

        // (b) counted drain: the (up to) 8 outstanding vmem are tile t+1's;
        //     everything for tile t has landed. Raw s_barrier: all waves' DMAs
        //     for tile t are in LDS.
        if (!last) { __asm__ volatile("s_waitcnt vmcnt(8)" ::: "memory"); }
        else       { __asm__ volatile("s_waitcnt vmcnt(0)" ::: "memory"); }
        __builtin_amdgcn_s_barrier();
        __asm__ volatile("" ::: "memory");

        // (c) QK^T: K-frags from shared LDS (contiguous 1KB b128 reads)
        f32x4 accqk[4];
#pragma unroll
        for (int cs = 0; cs < 4; ++cs) {
            f32x4 acc = (f32x4){0.f, 0.f, 0.f, 0.f};
#pragma unroll
            for (int ks = 0; ks < 2; ++ks) {
                s16x8 bK = *(const s16x8*)&kb[bu][(cs * 2 + ks) * 512 + lane * 8];
                acc = __builtin_amdgcn_mfma_f32_16x16x32_bf16(aQ[ks], bK, acc, 0, 0, 0);
            }
            accqk[cs] = acc;
        }

        // (d) epilogue: keep-bit via in-wave bpermute on um[bu]; floor; -> pb
#pragma unroll
        for (int cs = 0; cs < 4; ++cs) {
#pragma unroll
            for (int rg = 0; rg < 4; ++rg) {
                const int mv = __builtin_amdgcn_ds_bpermute(
                    (rg * 16 + cs * 4) * 4 + bidx0, (int)um[bu]);
                const float t = ((((unsigned)mv) >> bsel) & 1u) ? accqk[cs][rg] : 0.0f;
                const float r = floorf(t * rr[rg]);
                lsum += r;
                pw[(quad * 4 + rg) * LDP + cs * 16 + n16] = (short)f2bf(t * r);
            }
        }

        // (e) within-wave LDS drain for pb
        __builtin_amdgcn_wave_barrier();
        __asm__ volatile("s_waitcnt lgkmcnt(0)" ::: "memory");
        __builtin_amdgcn_wave_barrier();

        // (f) PV: V-frags from shared LDS
#pragma unroll
        for (int ksj = 0; ksj < 2; ++ksj) {
            s16x8 aP = *(const s16x8*)&pw[n16 * LDP + ksj * 32 + quad * 8];
#pragma unroll
            for (int ds = 0; ds < 4; ++ds) {
                s16x8 bV = *(const s16x8*)&vb[bu][(ksj * 4 + ds) * 512 + lane * 8];
                accO[ds] = __builtin_amdgcn_mfma_f32_16x16x32_bf16(aP, bV, accO[ds], 0, 0, 0);
            }
        }

        // (g) pack next tile's u mask (loads have had the whole tile to land)
        if (!last) {
            unsigned m = 0;
#pragma unroll
            for (int q = 0; q < 4; ++q) {
                m |= (un[q].x >= 0.1f ? 1u : 0u) << (q * 4 + 0);
                m |= (un[q].y >= 0.1f ? 1u : 0u) << (q * 4 + 1);
                m |= (un[q].z >= 0.1f ? 1u : 0u) << (q * 4 + 2);
                m |= (un[q].w >= 0.1f ? 1u : 0u) << (q * 4 + 3);
            }
            um[nb] = m;
        }

        // (h) all waves done reading buf bu before next iter's DMA overwrites it
        __asm__ volatile("" ::: "memory");
        __builtin_amdgcn_s_barrier();
        __asm__ volatile("" ::: "memory");
    }

    // deterministic partial stores (full 64B segments)
    float* op = Opart + (size_t)ic * S * D;
#pragma unroll
    for (int ds = 0; ds < 4; ++ds) {
        const int d = ds * 16 + n16;
#pragma unroll
        for (int rg = 0; rg < 4; ++rg) {
            const int i = i0w + quad * 4 + rg;
            op[(size_t)i * D + d] = accO[ds][rg];
        }
    }

    // sum(r): wave shuffle -> LDS -> one int atomic per block
    for (int off = 32; off; off >>= 1) lsum += __shfl_down(lsum, off);
    if (lane == 0) red[w] = (int)lsum;
    __syncthreads();
    if (tid == 0) atomicAdd(sumr, red[0] + red[1] + red[2] + red[3]);
}

// ---- reduce partials over NCHUNK + apply 1/R ----
__global__ void reduce_out(const float* __restrict__ Opart,
                           const int* __restrict__ sumr,
                           float* __restrict__ out) {
    const int idx = blockIdx.x * 256 + threadIdx.x;   // 65536 float4 groups
    const float invR = 1.0f / (float)(*sumr);         // |R| < 2^24: exact
    float sx = 0.f, sy = 0.f, sz = 0.f, sw = 0.f;
#pragma unroll
    for (int c = 0; c < NCHUNK; ++c) {
        const float4 v = ((const float4*)(Opart + (size_t)c * S * D))[idx];
        sx += v.x; sy += v.y; sz += v.z; sw += v.w;
    }
    float4 o; o.x = sx * invR; o.y = sy * invR; o.z = sz * invR; o.w = sw * invR;
    ((float4*)out)[idx] = o;
}

extern "C" void kernel_launch(void* const* d_in, const int* in_sizes, int n_in,
                              void* d_out, int out_size, void* d_ws, size_t ws_size,
                              hipStream_t stream) {
    (void)in_sizes; (void)n_in; (void)out_size; (void)ws_size;
    const float* Q  = (const float*)d_in[0];
    const float* Kf = (const float*)d_in[1];
    const float* V  = (const float*)d_in[2];
    const float* Ud = (const float*)d_in[3];
    const float* RR = (const float*)d_in[4];
    float* out = (float*)d_out;

    // ws layout: Opart 8MB | Qbf 512KB | Kbf 512KB | VTbf 512KB | sumr
    char* ws = (char*)d_ws;
    float* Opart = (float*)ws;                                  // 8 MB
    short* Qbf  = (short*)(ws + (8u << 20));
    short* Kbf  = (short*)(ws + (8u << 20) + (512u << 10));
    short* VTbf = (short*)(ws + (8u << 20) + (1024u << 10));
    int*   sumr = (int*)  (ws + (8u << 20) + (1536u << 10));

    prep_all<<<dim3(576), dim3(256), 0, stream>>>(Q, Kf, V, Qbf, Kbf, VTbf, sumr);
    fused_main<<<dim3(64 * NCHUNK), dim3(256), 0, stream>>>(
        Qbf, Kbf, VTbf, Ud, RR, Opart, sumr);
    reduce_out<<<dim3(256), dim3(256), 0, stream>>>(Opart, sumr, out);
}

// Round 12
// 120.748 us; speedup vs baseline: 1.4898x; 1.0038x over previous
//
#include <hip/hip_runtime.h>
#include <stdint.h>

// S=4096, D=64.  out = (t * floor(t*rr)/R) @ V,  t = (QK^T*8) * dropout_keep/0.9
// R12 = R11 (global_load_lds staging, fragment-major LDS, counted vmcnt,
// raw s_barrier) with JT 64->128: halves barriers/lgkm-drains/loop overhead
// at identical total MFMA+VMEM work. LDS fit via SINGLE-buffered vb (V(t+1)
// DMA issued after B2 of tile t -> all waves past PV; landed-check is the
// top-of-tile vmcnt(12)). kb stays double-buffered. u stays direct-b128 +
// 32-bit pack + bpermute delivery. Issue order: u, K-DMA (top); pack, V-DMA
// (bottom) so the pack's compiler wait never drains young prefetches.

#define S 4096
#define D 64
#define NCHUNK 8              // grid = 64 i-blocks * 8 chunks = 512 blocks
#define JCHUNK (S / NCHUNK)   // 512
#define JT 128
#define NTILES (JCHUNK / JT)  // 4
#define LDP 132               // pb pitch (shorts): 4 quads -> 4 distinct bank groups
#define KSCALE (8.0f / 0.9f)

typedef float f32x4 __attribute__((ext_vector_type(4)));
typedef short s16x8 __attribute__((ext_vector_type(8)));
typedef unsigned short u16x4 __attribute__((ext_vector_type(4)));
typedef const __attribute__((address_space(1))) unsigned g_u32;
typedef __attribute__((address_space(3))) unsigned lds_u32;

__device__ inline unsigned short f2bf(float f) {
    union { float f; unsigned u; } v; v.f = f;
    unsigned r = v.u + 0x7fffu + ((v.u >> 16) & 1u);
    return (unsigned short)(r >> 16);
}

// ---- prep: Q->bf16, K->bf16*KSCALE (blocks 0..511), V->V^T (512..575) ----
__global__ void prep_all(const float* __restrict__ Q,
                         const float* __restrict__ Kf,
                         const float* __restrict__ V,
                         short* __restrict__ Qbf, short* __restrict__ Kbf,
                         short* __restrict__ VTbf, int* __restrict__ sumr) {
    __shared__ short tile[64 * 68];
    const int b   = blockIdx.x;
    const int tid = threadIdx.x;
    if (b == 0 && tid == 0) *sumr = 0;

    if (b < 512) {
        const int idx = b * 256 + tid;               // 131072 float4 slots
        if (idx < 65536) {
            float4 v = ((const float4*)Q)[idx];
            u16x4 o; o[0] = f2bf(v.x); o[1] = f2bf(v.y); o[2] = f2bf(v.z); o[3] = f2bf(v.w);
            ((u16x4*)Qbf)[idx] = o;
        } else {
            const int k = idx - 65536;
            float4 v = ((const float4*)Kf)[k];
            u16x4 o; o[0] = f2bf(v.x * KSCALE); o[1] = f2bf(v.y * KSCALE);
                     o[2] = f2bf(v.z * KSCALE); o[3] = f2bf(v.w * KSCALE);
            ((u16x4*)Kbf)[k] = o;
        }
    } else {
        const int j0 = (b - 512) * 64;
#pragma unroll
        for (int it = 0; it < 4; ++it) {
            const int f4 = tid + it * 256;
            const int row = f4 >> 4, c4 = (f4 & 15) * 4;
            float4 v = *(const float4*)&V[(size_t)(j0 + row) * D + c4];
            tile[(c4 + 0) * 68 + row] = (short)f2bf(v.x);
            tile[(c4 + 1) * 68 + row] = (short)f2bf(v.y);
            tile[(c4 + 2) * 68 + row] = (short)f2bf(v.z);
            tile[(c4 + 3) * 68 + row] = (short)f2bf(v.w);
        }
        __syncthreads();
#pragma unroll
        for (int it = 0; it < 4; ++it) {
            const int f4 = tid + it * 256;
            const int d = f4 >> 4, o4 = (f4 & 15) * 4;
            u16x4 w = *(const u16x4*)&tile[d * 68 + o4];
            *(u16x4*)&VTbf[(size_t)d * S + j0 + o4] = w;
        }
    }
}

// ---- main ----
__launch_bounds__(256, 2)
__global__ void fused_main(const short* __restrict__ Qbf,
                           const short* __restrict__ Kbf,
                           const short* __restrict__ VTbf,
                           const float* __restrict__ Ud,
                           const float* __restrict__ RR,
                           float* __restrict__ Opart,            // [NCHUNK][S][D]
                           int* __restrict__ sumr)
{
    __shared__ short kb[2][16 * 512];    // K tile 128x64, fragment-major (frag=1KB)
    __shared__ short vb[16 * 512];       // V^T tile 64x128, fragment-major, SINGLE buf
    __shared__ short pb[4 * 16 * LDP];   // per-wave P relayout (16 x 128)
    __shared__ int red[4];

    const int tid  = threadIdx.x;
    const int w    = tid >> 6;
    const int lane = tid & 63;
    const int quad = lane >> 4;
    const int n16  = lane & 15;

    const int ib  = blockIdx.x & 63;
    const int ic  = blockIdx.x >> 6;     // 0..NCHUNK-1
    const int i0w = ib * 64 + w * 16;
    const int jbase = ic * JCHUNK;

    const float* uwb = Ud + (size_t)i0w * S;

    s16x8 aQ[2];
#pragma unroll
    for (int ks = 0; ks < 2; ++ks)
        aQ[ks] = *(const s16x8*)&Qbf[(size_t)(i0w + n16) * D + ks * 32 + quad * 8];

    float rr[4];
#pragma unroll
    for (int rg = 0; rg < 4; ++rg) rr[rg] = RR[i0w + quad * 4 + rg];

    f32x4 accO[4];
#pragma unroll
    for (int ds = 0; ds < 4; ++ds) accO[ds] = (f32x4){0.f, 0.f, 0.f, 0.f};

    float lsum = 0.f;
    short* pw = pb + w * 16 * LDP;

    unsigned um[2];                        // 32 keep-bits per lane per tile
    const int bsel  = quad * 4 + (n16 & 3);      // + h*16 at use
    const int bidx0 = (n16 >> 2) * 4;

    // ---- prologue: tile 0 (u first, then K, then V; pack last) ----
    float4 un[8];
    {
        const int j0 = jbase;
#pragma unroll
        for (int h = 0; h < 2; ++h)
#pragma unroll
            for (int q = 0; q < 4; ++q)
                un[h * 4 + q] = *(const float4*)&uwb[(size_t)(q * 4 + quad) * S + j0 + h * 64 + n16 * 4];
#pragma unroll
        for (int p = 0; p < 4; ++p) {
            const int e = w * 4 + p;
            __builtin_amdgcn_global_load_lds(
                (g_u32*)&Kbf[(size_t)(j0 + (e >> 1) * 16 + n16) * D + (e & 1) * 32 + quad * 8],
                (lds_u32*)&kb[0][e * 512], 16, 0, 0);
        }
#pragma unroll
        for (int p = 0; p < 4; ++p) {
            const int e = w * 4 + p;
            __builtin_amdgcn_global_load_lds(
                (g_u32*)&VTbf[(size_t)((e & 3) * 16 + n16) * S + j0 + (e >> 2) * 32 + quad * 8],
                (lds_u32*)&vb[e * 512], 16, 0, 0);
        }
        unsigned m = 0;
#pragma unroll
        for (int e = 0; e < 8; ++e) {     // pack waits u0; K0/V0 (younger) stay in flight
            m |= (un[e].x >= 0.1f ? 1u : 0u) << (e * 4 + 0);
            m |= (un[e].y >= 0.1f ? 1u : 0u) << (e * 4 + 1);
            m |= (un[e].z >= 0.1f ? 1u : 0u) << (e * 4 + 2);
            m |= (un[e].w >= 0.1f ? 1u : 0u) << (e * 4 + 3);
        }
        um[0] = m;
    }

#pragma unroll
    for (int jt = 0; jt < NTILES; ++jt) {
        const int bu = jt & 1;
        const int nb = bu ^ 1;
        const int j0 = jbase + jt * JT;
        const bool last = (jt + 1 == NTILES);

        // (a) NEXT tile: u loads first, then K-DMA into kb[nb]
        if (!last) {
            const int j1 = j0 + JT;
#pragma unroll
            for (int h = 0; h < 2; ++h)
#pragma unroll
                for (int q = 0; q < 4; ++q)
                    un[h * 4 + q] = *(const float4*)&uwb[(size_t)(q * 4 + quad) * S + j1 + h * 64 + n16 * 4];
#pragma unroll
            for (int p = 0; p < 4; ++p) {
                const int e = w * 4 + p;
                __builtin_amdgcn_global_load_lds(
                    (g_u32*)&Kbf[(size_t)(j1 + (e >> 1) * 16 + n16) * D + (e & 1) * 32 + quad * 8],
                    (lds_u32*)&kb[nb][e * 512], 16, 0, 0);
            }
        }

        // (b) counted drain: the 12 youngest (u(t+1) 8 + K(t+1) 4) may remain;
        //     everything older — K(t), V(t), stragglers — must land.
        if (!last) { __asm__ volatile("s_waitcnt vmcnt(12)" ::: "memory"); }
        else       { __asm__ volatile("s_waitcnt vmcnt(0)"  ::: "memory"); }
        __builtin_amdgcn_s_barrier();
        __asm__ volatile("" ::: "memory");

        // (c) QK^T + fused epilogue per 16-col subtile (accqk live = 4 regs)
#pragma unroll
        for (int cs = 0; cs < 8; ++cs) {
            f32x4 acc = (f32x4){0.f, 0.f, 0.f, 0.f};
#pragma unroll
            for (int ks = 0; ks < 2; ++ks) {
                s16x8 bK = *(const s16x8*)&kb[bu][(cs * 2 + ks) * 512 + lane * 8];
                acc = __builtin_amdgcn_mfma_f32_16x16x32_bf16(aQ[ks], bK, acc, 0, 0, 0);
            }
            const int h = cs >> 2, c4 = cs & 3;
#pragma unroll
            for (int rg = 0; rg < 4; ++rg) {
                const int mv = __builtin_amdgcn_ds_bpermute(
                    (rg * 16 + c4 * 4) * 4 + bidx0, (int)um[bu]);
                const float t = ((((unsigned)mv) >> (h * 16 + bsel)) & 1u) ? acc[rg] : 0.0f;
                const float r = floorf(t * rr[rg]);
                lsum += r;
                pw[(quad * 4 + rg) * LDP + cs * 16 + n16] = (short)f2bf(t * r);
            }
        }

        // (d) within-wave LDS drain for pb
        __builtin_amdgcn_wave_barrier();
        __asm__ volatile("s_waitcnt lgkmcnt(0)" ::: "memory");
        __builtin_amdgcn_wave_barrier();

        // (e) PV over 128-wide contraction
#pragma unroll
        for (int ksj = 0; ksj < 4; ++ksj) {
            s16x8 aP = *(const s16x8*)&pw[n16 * LDP + ksj * 32 + quad * 8];
#pragma unroll
            for (int ds = 0; ds < 4; ++ds) {
                s16x8 bV = *(const s16x8*)&vb[(ksj * 4 + ds) * 512 + lane * 8];
                accO[ds] = __builtin_amdgcn_mfma_f32_16x16x32_bf16(aP, bV, accO[ds], 0, 0, 0);
            }
        }

        // (f) all waves past PV before vb is overwritten
        __asm__ volatile("" ::: "memory");
        __builtin_amdgcn_s_barrier();
        __asm__ volatile("" ::: "memory");

        // (g) pack u(t+1) (waits only u regs), THEN issue V(t+1) into vb
        if (!last) {
            unsigned m = 0;
#pragma unroll
            for (int e = 0; e < 8; ++e) {
                m |= (un[e].x >= 0.1f ? 1u : 0u) << (e * 4 + 0);
                m |= (un[e].y >= 0.1f ? 1u : 0u) << (e * 4 + 1);
                m |= (un[e].z >= 0.1f ? 1u : 0u) << (e * 4 + 2);
                m |= (un[e].w >= 0.1f ? 1u : 0u) << (e * 4 + 3);
            }
            um[nb] = m;
            const int j1 = j0 + JT;
#pragma unroll
            for (int p = 0; p < 4; ++p) {
                const int e = w * 4 + p;
                __builtin_amdgcn_global_load_lds(
                    (g_u32*)&VTbf[(size_t)((e & 3) * 16 + n16) * S + j1 + (e >> 2) * 32 + quad * 8],
                    (lds_u32*)&vb[e * 512], 16, 0, 0);
            }
        }
    }

    // deterministic partial stores (full 64B segments)
    float* op = Opart + (size_t)ic * S * D;
#pragma unroll
    for (int ds = 0; ds < 4; ++ds) {
        const int d = ds * 16 + n16;
#pragma unroll
        for (int rg = 0; rg < 4; ++rg) {
            const int i = i0w + quad * 4 + rg;
            op[(size_t)i * D + d] = accO[ds][rg];
        }
    }

    // sum(r): wave shuffle -> LDS -> one int atomic per block
    for (int off = 32; off; off >>= 1) lsum += __shfl_down(lsum, off);
    if (lane == 0) red[w] = (int)lsum;
    __syncthreads();
    if (tid == 0) atomicAdd(sumr, red[0] + red[1] + red[2] + red[3]);
}

// ---- reduce partials over NCHUNK + apply 1/R ----
__global__ void reduce_out(const float* __restrict__ Opart,
                           const int* __restrict__ sumr,
                           float* __restrict__ out) {
    const int idx = blockIdx.x * 256 + threadIdx.x;   // 65536 float4 groups
    const float invR = 1.0f / (float)(*sumr);         // |R| < 2^24: exact
    float sx = 0.f, sy = 0.f, sz = 0.f, sw = 0.f;
#pragma unroll
    for (int c = 0; c < NCHUNK; ++c) {
        const float4 v = ((const float4*)(Opart + (size_t)c * S * D))[idx];
        sx += v.x; sy += v.y; sz += v.z; sw += v.w;
    }
    float4 o; o.x = sx * invR; o.y = sy * invR; o.z = sz * invR; o.w = sw * invR;
    ((float4*)out)[idx] = o;
}

extern "C" void kernel_launch(void* const* d_in, const int* in_sizes, int n_in,
                              void* d_out, int out_size, void* d_ws, size_t ws_size,
                              hipStream_t stream) {
    (void)in_sizes; (void)n_in; (void)out_size; (void)ws_size;
    const float* Q  = (const float*)d_in[0];
    const float* Kf = (const float*)d_in[1];
    const float* V  = (const float*)d_in[2];
    const float* Ud = (const float*)d_in[3];
    const float* RR = (const float*)d_in[4];
    float* out = (float*)d_out;

    // ws layout: Opart 8MB | Qbf 512KB | Kbf 512KB | VTbf 512KB | sumr
    char* ws = (char*)d_ws;
    float* Opart = (float*)ws;                                  // 8 MB
    short* Qbf  = (short*)(ws + (8u << 20));
    short* Kbf  = (short*)(ws + (8u << 20) + (512u << 10));
    short* VTbf = (short*)(ws + (8u << 20) + (1024u << 10));
    int*   sumr = (int*)  (ws + (8u << 20) + (1536u << 10));

    prep_all<<<dim3(576), dim3(256), 0, stream>>>(Q, Kf, V, Qbf, Kbf, VTbf, sumr);
    fused_main<<<dim3(64 * NCHUNK), dim3(256), 0, stream>>>(
        Qbf, Kbf, VTbf, Ud, RR, Opart, sumr);
    reduce_out<<<dim3(256), dim3(256), 0, stream>>>(Opart, sumr, out);
}